// Round 10
// baseline (399.491 us; speedup 1.0000x reference)
//
#include <hip/hip_runtime.h>
#include <hip/hip_bf16.h>

#define NN 100000   // nodes
#define NE 800000   // edges (without self loops)
#define E2 900000   // edges + self loops
#define F  128      // KGE
#define NB 8        // batch
#define SEQ 1024
#define HID 1024
#define DWN 256
#define TP 32
#define NCB 196     // coarse dst-buckets of 512 nodes (196*512 = 100352 >= NN)
#define CCAP 5120   // slab cap per bucket (expected 4592, sigma 68 -> 7.8 sigma slack)
#define EPB 4096    // edges per k_part block

typedef __attribute__((ext_vector_type(4))) float f32x4;
typedef __attribute__((ext_vector_type(8))) short s16x8;

__device__ __forceinline__ float BL(uint u) { return __uint_as_float(u << 16); }
__device__ __forceinline__ float BH(uint u) { return __uint_as_float(u & 0xffff0000u); }
__device__ __forceinline__ uint PK(float lo, float hi) {
    __hip_bfloat16 a = __float2bfloat16(lo);
    __hip_bfloat16 b = __float2bfloat16(hi);
    return (uint)(*(ushort*)&a) | ((uint)(*(ushort*)&b) << 16);
}
__device__ __forceinline__ ushort B1(float v) {
    __hip_bfloat16 a = __float2bfloat16(v);
    return *(ushort*)&a;
}
// floor(a/L) via float reciprocal + fixup; exact for 0<=a<2^24, 0<L<2^24
__device__ __forceinline__ int fdivq(int a, int L, float rcL) {
    int t = __float2int_rz((float)a * rcL);
    if (t * L > a) t--;
    else if ((t + 1) * L <= a) t++;
    return t;
}

// ---------------- batch offsets from sorted batch_ids ----------------
__global__ void k_offsets(const int* __restrict__ bids, int* __restrict__ offs) {
    int n = blockIdx.x * 256 + threadIdx.x;
    if (n >= NN) return;
    int b = bids[n];
    if (n == 0) offs[0] = 0;
    else if (bids[n - 1] != b) offs[b] = n;
    if (n == NN - 1) offs[b + 1] = NN;
}

// ---------------- embedding gather: x[n] = bf16(emb[graph_x[n]]) ----------------
__global__ void k_embed(const int* __restrict__ gx, const float* __restrict__ emb,
                        ushort* __restrict__ x) {
    int i = blockIdx.x * 256 + threadIdx.x;   // over NN*16 chunks of 8 cols
    int n = i >> 4, c = i & 15;
    const float4* src = (const float4*)(emb + (size_t)gx[n] * F + c * 8);
    float4 a = src[0], b = src[1];
    uint4 o;
    o.x = PK(a.x, a.y); o.y = PK(a.z, a.w);
    o.z = PK(b.x, b.y); o.w = PK(b.z, b.w);
    *(uint4*)&x[(size_t)n * F + c * 8] = o;
}

// ---------------- W transpose+bf16: wt[l][col][k] = bf16(W[l][k][col]) ----------
__global__ void k_wconv(const float* __restrict__ W, ushort* __restrict__ wt) {
    int l = blockIdx.x >> 7, col = blockIdx.x & 127, k = threadIdx.x;
    wt[l * 16384 + col * 128 + k] = B1(W[l * 16384 + k * 128 + col]);
}

// ---------------- CSR pass 1: partition edges into coarse buckets ----------------
__global__ __launch_bounds__(256) void k_part(const int* __restrict__ ei,
                                              int* __restrict__ bcur,
                                              uint* __restrict__ stage) {
    __shared__ int lcnt[NCB], gbase[NCB], lpos[NCB];
    int t = threadIdx.x;
    int e0 = blockIdx.x * EPB;
    for (int i = t; i < NCB; i += 256) { lcnt[i] = 0; lpos[i] = 0; }
    __syncthreads();
    for (int i = t; i < EPB; i += 256) {
        int e = e0 + i; if (e >= E2) break;
        int dst = (e < NE) ? ei[NE + e] : (e - NE);
        atomicAdd(&lcnt[dst >> 9], 1);
    }
    __syncthreads();
    for (int i = t; i < NCB; i += 256)
        if (lcnt[i] > 0) gbase[i] = atomicAdd(&bcur[i], lcnt[i]);
    __syncthreads();
    for (int i = t; i < EPB; i += 256) {
        int e = e0 + i; if (e >= E2) break;
        int src, dst;
        if (e < NE) { src = ei[e]; dst = ei[NE + e]; }
        else        { src = dst = e - NE; }
        int b = dst >> 9;
        int r = atomicAdd(&lpos[b], 1);
        int pos = gbase[b] + r;
        if (pos < CCAP) stage[(size_t)b * CCAP + pos] = ((uint)src << 9) | (uint)(dst & 511);
    }
}

// ---------------- bucket base scan ----------------
__global__ void k_cboff(const int* __restrict__ bcur, int* __restrict__ cbase,
                        int* __restrict__ indptr) {
    if (threadIdx.x == 0) {
        int r = 0;
        for (int i = 0; i < NCB; i++) { cbase[i] = r; r += min(bcur[i], CCAP); }
        cbase[NCB] = r;
        indptr[NN] = r;
    }
}

// ---------------- CSR pass 2: per-bucket sort (LDS hist + scan + scatter) -------
// srcs stores WORD offsets (src*64) so k_agg's gather needs no 64-bit mul.
__global__ __launch_bounds__(256) void k_sort2(
    const uint* __restrict__ stage, const int* __restrict__ bcur,
    const int* __restrict__ cbase, int* __restrict__ indptr,
    int* __restrict__ srcs) {
    __shared__ int lcur[512], sa[256], sb[256];
    __shared__ uint sorted[CCAP];
    int g = blockIdx.x, t = threadIdx.x;
    int ecnt = min(bcur[g], CCAP);
    int base = cbase[g];
    const uint* slab = stage + (size_t)g * CCAP;
    lcur[t] = 0; lcur[t + 256] = 0;
    __syncthreads();
    for (int i = t; i < ecnt; i += 256)
        atomicAdd(&lcur[slab[i] & 511u], 1);
    __syncthreads();
    int c0 = lcur[2 * t], c1 = lcur[2 * t + 1];
    sa[t] = c0 + c1; __syncthreads();
    int *s = sa, *d = sb;
    for (int off = 1; off < 256; off <<= 1) {
        int v = s[t]; if (t >= off) v += s[t - off];
        d[t] = v; __syncthreads();
        int* tmp = s; s = d; d = tmp;
    }
    int excl = s[t] - (c0 + c1);
    int n0 = g * 512 + 2 * t;
    if (n0 < NN) indptr[n0] = base + excl;
    if (n0 + 1 < NN) indptr[n0 + 1] = base + excl + c0;
    __syncthreads();
    lcur[2 * t] = excl; lcur[2 * t + 1] = excl + c0;
    __syncthreads();
    for (int i = t; i < ecnt; i += 256) {
        uint p = slab[i];
        int pos = atomicAdd(&lcur[p & 511u], 1);
        sorted[pos] = p >> 9;
    }
    __syncthreads();
    for (int i = t; i < ecnt; i += 256)
        srcs[base + i] = (int)(sorted[i] << 6);
}

// ---------------- MFMA GEMM: h = x @ W (bf16), fused hs epilogue ----------------
__global__ __launch_bounds__(256) void k_gemm(
    const ushort* __restrict__ xb, const ushort* __restrict__ wt,
    const float* __restrict__ a_s, const float* __restrict__ a_d,
    ushort* __restrict__ hb, float* __restrict__ hs_src, float* __restrict__ hs_dst) {
    __shared__ uint4 As[128 * 16];
    __shared__ uint4 Bs[128 * 16];
    const int tid = threadIdx.x;
    const int wave = tid >> 6, lane = tid & 63;
    const int row0 = blockIdx.x * 128;
    const int lr = lane & 15, lg = lane >> 4;

    #pragma unroll
    for (int p = 0; p < 8; p++) {
        int id = p * 256 + tid;
        int row = id >> 4, c16 = id & 15;
        int rg = row0 + row; if (rg >= NN) rg = NN - 1;
        As[row * 16 + (c16 ^ (row & 7))] = *(const uint4*)&xb[(size_t)rg * F + c16 * 8];
        Bs[row * 16 + (c16 ^ (row & 7))] = *(const uint4*)&wt[row * F + c16 * 8];
    }
    __syncthreads();

    f32x4 acc[2][8];
    #pragma unroll
    for (int m = 0; m < 2; m++)
        #pragma unroll
        for (int n = 0; n < 8; n++) acc[m][n] = (f32x4){0.f, 0.f, 0.f, 0.f};

    #pragma unroll
    for (int kt = 0; kt < 4; kt++) {
        s16x8 a[2], b[8];
        #pragma unroll
        for (int m = 0; m < 2; m++) {
            int row = 32 * wave + 16 * m + lr;
            a[m] = *reinterpret_cast<const s16x8*>(&As[row * 16 + ((kt * 4 + lg) ^ (row & 7))]);
        }
        #pragma unroll
        for (int n = 0; n < 8; n++) {
            int col = 16 * n + lr;
            b[n] = *reinterpret_cast<const s16x8*>(&Bs[col * 16 + ((kt * 4 + lg) ^ (col & 7))]);
        }
        #pragma unroll
        for (int m = 0; m < 2; m++)
            #pragma unroll
            for (int n = 0; n < 8; n++)
                acc[m][n] = __builtin_amdgcn_mfma_f32_16x16x32_bf16(a[m], b[n], acc[m][n], 0, 0, 0);
    }

    float asv[8], adv[8];
    #pragma unroll
    for (int n = 0; n < 8; n++) { asv[n] = a_s[16 * n + lr]; adv[n] = a_d[16 * n + lr]; }

    #pragma unroll
    for (int m = 0; m < 2; m++) {
        #pragma unroll
        for (int r = 0; r < 4; r++) {
            int rg = row0 + 32 * wave + 16 * m + lg * 4 + r;
            bool ok = rg < NN;
            float ps = 0.f, pd = 0.f;
            #pragma unroll
            for (int n = 0; n < 8; n++) {
                float v = acc[m][n][r];
                if (ok) hb[(size_t)rg * F + 16 * n + lr] = B1(v);
                ps += v * asv[n]; pd += v * adv[n];
            }
            #pragma unroll
            for (int msk = 8; msk >= 1; msk >>= 1) {
                ps += __shfl_xor(ps, msk);
                pd += __shfl_xor(pd, msk);
            }
            if (ok && lr == 0) { hs_src[rg] = ps; hs_dst[rg] = pd; }
        }
    }
}

// ---------------- per-node GAT aggregation (softmax over in-edges) ----------------
// srcs holds word offsets; (off,exp) staged in LDS, read back as uint4 pairs;
// gather unrolled 8 edges deep with 4 independent float2 accumulators.
__global__ __launch_bounds__(256) void k_agg(
    const ushort* __restrict__ hb, const int* __restrict__ srcs,
    const int* __restrict__ indptr, const float* __restrict__ hs_src,
    const float* __restrict__ hs_dst, const float* __restrict__ bias,
    ushort* __restrict__ xout, int do_relu) {
    __shared__ uint seS[4][128];
    int wave = threadIdx.x >> 6, lane = threadIdx.x & 63;
    int i = blockIdx.x * 4 + wave;
    if (i >= NN) return;
    int p0 = indptr[i], p1 = indptr[i + 1];
    int deg = p1 - p0;
    float hd = hs_dst[i];
    const uint* hbw = (const uint*)hb;
    float2 a0 = {0.f, 0.f}, a1 = {0.f, 0.f}, a2 = {0.f, 0.f}, a3 = {0.f, 0.f};
    float dl = 0.f;

    if (deg <= 64) {
        uint off = 0; float e = -1e30f;
        if (lane < deg) {
            off = (uint)srcs[p0 + lane];
            float t0 = hs_src[off >> 6] + hd;
            e = t0 > 0.f ? t0 : 0.2f * t0;
        }
        float m = e;
        #pragma unroll
        for (int o = 32; o > 0; o >>= 1) m = fmaxf(m, __shfl_xor(m, o));
        float ex = (lane < deg) ? __expf(e - m) : 0.f;
        dl = ex;
        ((uint2*)seS[wave])[lane] = make_uint2(off, __float_as_uint(ex));
        const uint4* ser = (const uint4*)seS[wave];
        int np = (deg + 1) >> 1;
        int j2 = 0;
        for (; j2 + 4 <= np; j2 += 4) {
            uint4 q0 = ser[j2], q1 = ser[j2 + 1], q2 = ser[j2 + 2], q3 = ser[j2 + 3];
            uint v00 = hbw[q0.x + lane], v01 = hbw[q0.z + lane];
            uint v10 = hbw[q1.x + lane], v11 = hbw[q1.z + lane];
            uint v20 = hbw[q2.x + lane], v21 = hbw[q2.z + lane];
            uint v30 = hbw[q3.x + lane], v31 = hbw[q3.z + lane];
            float e00 = __uint_as_float(q0.y), e01 = __uint_as_float(q0.w);
            float e10 = __uint_as_float(q1.y), e11 = __uint_as_float(q1.w);
            float e20 = __uint_as_float(q2.y), e21 = __uint_as_float(q2.w);
            float e30 = __uint_as_float(q3.y), e31 = __uint_as_float(q3.w);
            a0.x += e00 * BL(v00); a0.y += e00 * BH(v00);
            a1.x += e10 * BL(v10); a1.y += e10 * BH(v10);
            a2.x += e20 * BL(v20); a2.y += e20 * BH(v20);
            a3.x += e30 * BL(v30); a3.y += e30 * BH(v30);
            a0.x += e01 * BL(v01); a0.y += e01 * BH(v01);
            a1.x += e11 * BL(v11); a1.y += e11 * BH(v11);
            a2.x += e21 * BL(v21); a2.y += e21 * BH(v21);
            a3.x += e31 * BL(v31); a3.y += e31 * BH(v31);
        }
        for (; j2 < np; j2++) {
            uint4 q = ser[j2];
            uint v0 = hbw[q.x + lane], v1 = hbw[q.z + lane];
            float e0 = __uint_as_float(q.y), e1 = __uint_as_float(q.w);
            a0.x += e0 * BL(v0); a0.y += e0 * BH(v0);
            a1.x += e1 * BL(v1); a1.y += e1 * BH(v1);
        }
    } else {
        float m = -1e30f;
        for (int p = p0 + lane; p < p1; p += 64) {
            uint off = (uint)srcs[p];
            float e = hs_src[off >> 6] + hd;
            e = e > 0.f ? e : 0.2f * e;
            m = fmaxf(m, e);
        }
        #pragma unroll
        for (int o = 32; o > 0; o >>= 1) m = fmaxf(m, __shfl_xor(m, o));
        for (int base = p0; base < p1; base += 64) {
            int cn = min(64, p1 - base);
            uint off = 0; float ex = 0.f;
            if (lane < cn) {
                off = (uint)srcs[base + lane];
                float e = hs_src[off >> 6] + hd;
                e = e > 0.f ? e : 0.2f * e;
                ex = __expf(e - m);
            }
            dl += ex;
            ((uint2*)seS[wave])[lane] = make_uint2(off, __float_as_uint(ex));
            const uint4* ser = (const uint4*)seS[wave];
            int np = (cn + 1) >> 1;
            int j2 = 0;
            for (; j2 + 4 <= np; j2 += 4) {
                uint4 q0 = ser[j2], q1 = ser[j2 + 1], q2 = ser[j2 + 2], q3 = ser[j2 + 3];
                uint v00 = hbw[q0.x + lane], v01 = hbw[q0.z + lane];
                uint v10 = hbw[q1.x + lane], v11 = hbw[q1.z + lane];
                uint v20 = hbw[q2.x + lane], v21 = hbw[q2.z + lane];
                uint v30 = hbw[q3.x + lane], v31 = hbw[q3.z + lane];
                float e00 = __uint_as_float(q0.y), e01 = __uint_as_float(q0.w);
                float e10 = __uint_as_float(q1.y), e11 = __uint_as_float(q1.w);
                float e20 = __uint_as_float(q2.y), e21 = __uint_as_float(q2.w);
                float e30 = __uint_as_float(q3.y), e31 = __uint_as_float(q3.w);
                a0.x += e00 * BL(v00); a0.y += e00 * BH(v00);
                a1.x += e10 * BL(v10); a1.y += e10 * BH(v10);
                a2.x += e20 * BL(v20); a2.y += e20 * BH(v20);
                a3.x += e30 * BL(v30); a3.y += e30 * BH(v30);
                a0.x += e01 * BL(v01); a0.y += e01 * BH(v01);
                a1.x += e11 * BL(v11); a1.y += e11 * BH(v11);
                a2.x += e21 * BL(v21); a2.y += e21 * BH(v21);
                a3.x += e31 * BL(v31); a3.y += e31 * BH(v31);
            }
            for (; j2 < np; j2++) {
                uint4 q = ser[j2];
                uint v0 = hbw[q.x + lane], v1 = hbw[q.z + lane];
                float e0 = __uint_as_float(q.y), e1 = __uint_as_float(q.w);
                a0.x += e0 * BL(v0); a0.y += e0 * BH(v0);
                a1.x += e1 * BL(v1); a1.y += e1 * BH(v1);
            }
        }
    }
    float accx = (a0.x + a1.x) + (a2.x + a3.x);
    float accy = (a0.y + a1.y) + (a2.y + a3.y);
    #pragma unroll
    for (int o = 32; o > 0; o >>= 1) dl += __shfl_xor(dl, o);
    float inv = 1.f / dl;
    float2 b2 = ((const float2*)bias)[lane];
    float ox = accx * inv + b2.x;
    float oy = accy * inv + b2.y;
    if (do_relu) { ox = fmaxf(ox, 0.f); oy = fmaxf(oy, 0.f); }
    ((uint*)xout)[(size_t)i * 64 + lane] = PK(ox, oy);
}

// ---------------- bin sums: ctx rows (x3 bf16, 128 cols) ----------------
__global__ __launch_bounds__(256) void k_binsum_ctx(
    const ushort* __restrict__ x3, const int* __restrict__ bids,
    const int* __restrict__ offs, const int* __restrict__ seq_len,
    float* __restrict__ s128) {
    int wid = blockIdx.x * 4 + (threadIdx.x >> 6);
    int lane = threadIdx.x & 63;
    int r0 = wid * 64;
    if (r0 >= NN) return;
    int r1 = min(r0 + 64, NN);
    float ax = 0.f, ay = 0.f;
    int cur = -1;
    int cb = -1, off = 0, C = 0, L = 1;
    float rcL = 1.f;
    for (int r = r0; r < r1; r++) {
        int b = bids[r];
        if (b != cb) {
            cb = b; off = offs[b]; C = offs[b + 1] - off; L = C + seq_len[b];
            rcL = 1.0f / (float)L;
        }
        int q = r - off;
        int tmin = fdivq(q * TP, L, rcL);
        int tmax = fdivq((q + 1) * TP - 1, L, rcL);
        uint v = ((const uint*)(x3 + (size_t)r * F))[lane];
        float vx = BL(v), vy = BH(v);
        int bin = b * TP + tmin;
        if (bin != cur) {
            if (cur >= 0) {
                atomicAdd(&s128[(size_t)cur * F + 2 * lane], ax);
                atomicAdd(&s128[(size_t)cur * F + 2 * lane + 1], ay);
            }
            cur = bin; ax = 0.f; ay = 0.f;
        }
        ax += vx; ay += vy;
        if (tmax != tmin) {
            atomicAdd(&s128[(size_t)(b * TP + tmax) * F + 2 * lane], vx);
            atomicAdd(&s128[(size_t)(b * TP + tmax) * F + 2 * lane + 1], vy);
        }
    }
    if (cur >= 0) {
        atomicAdd(&s128[(size_t)cur * F + 2 * lane], ax);
        atomicAdd(&s128[(size_t)cur * F + 2 * lane + 1], ay);
    }
}

// ---------------- bin sums: hidden rows (1024 cols), 8-row chunks ----------------
__global__ __launch_bounds__(256) void k_binsum_hid(
    const float* __restrict__ hidden, const int* __restrict__ offs,
    const int* __restrict__ seq_len, float* __restrict__ s1024) {
    int wid = blockIdx.x * 4 + (threadIdx.x >> 6);   // 0..1023
    int lane = threadIdx.x & 63;
    int b = wid >> 7;          // 128 chunks per batch
    int chunk = wid & 127;
    int sl = seq_len[b];
    int r0 = chunk * 8;
    if (r0 >= sl) return;
    int r1 = min(r0 + 8, sl);
    int C = offs[b + 1] - offs[b];
    int L = C + sl;
    float rcL = 1.0f / (float)L;
    float a[16];
    #pragma unroll
    for (int c = 0; c < 16; c++) a[c] = 0.f;
    int cur = -1;
    const float* hbase = hidden + (size_t)b * SEQ * HID;
    for (int r = r0; r < r1; r++) {
        int q = C + r;
        int tmin = fdivq(q * TP, L, rcL);
        int tmax = fdivq((q + 1) * TP - 1, L, rcL);
        const float4* row = (const float4*)(hbase + (size_t)r * HID);
        float4 v0 = row[lane], v1 = row[64 + lane], v2 = row[128 + lane], v3 = row[192 + lane];
        int bin = b * TP + tmin;
        if (bin != cur) {
            if (cur >= 0) {
                float* dst = s1024 + (size_t)cur * HID;
                #pragma unroll
                for (int c = 0; c < 4; c++) atomicAdd(&dst[4 * lane + c], a[c]);
                #pragma unroll
                for (int c = 0; c < 4; c++) atomicAdd(&dst[256 + 4 * lane + c], a[4 + c]);
                #pragma unroll
                for (int c = 0; c < 4; c++) atomicAdd(&dst[512 + 4 * lane + c], a[8 + c]);
                #pragma unroll
                for (int c = 0; c < 4; c++) atomicAdd(&dst[768 + 4 * lane + c], a[12 + c]);
            }
            cur = bin;
            #pragma unroll
            for (int c = 0; c < 16; c++) a[c] = 0.f;
        }
        a[0] += v0.x; a[1] += v0.y; a[2] += v0.z; a[3] += v0.w;
        a[4] += v1.x; a[5] += v1.y; a[6] += v1.z; a[7] += v1.w;
        a[8] += v2.x; a[9] += v2.y; a[10] += v2.z; a[11] += v2.w;
        a[12] += v3.x; a[13] += v3.y; a[14] += v3.z; a[15] += v3.w;
        if (tmax != tmin) {
            float* dst = s1024 + (size_t)(b * TP + tmax) * HID;
            atomicAdd(&dst[4 * lane + 0], v0.x); atomicAdd(&dst[4 * lane + 1], v0.y);
            atomicAdd(&dst[4 * lane + 2], v0.z); atomicAdd(&dst[4 * lane + 3], v0.w);
            atomicAdd(&dst[256 + 4 * lane + 0], v1.x); atomicAdd(&dst[256 + 4 * lane + 1], v1.y);
            atomicAdd(&dst[256 + 4 * lane + 2], v1.z); atomicAdd(&dst[256 + 4 * lane + 3], v1.w);
            atomicAdd(&dst[512 + 4 * lane + 0], v2.x); atomicAdd(&dst[512 + 4 * lane + 1], v2.y);
            atomicAdd(&dst[512 + 4 * lane + 2], v2.z); atomicAdd(&dst[512 + 4 * lane + 3], v2.w);
            atomicAdd(&dst[768 + 4 * lane + 0], v3.x); atomicAdd(&dst[768 + 4 * lane + 1], v3.y);
            atomicAdd(&dst[768 + 4 * lane + 2], v3.z); atomicAdd(&dst[768 + 4 * lane + 3], v3.w);
        }
    }
    if (cur >= 0) {
        float* dst = s1024 + (size_t)cur * HID;
        #pragma unroll
        for (int c = 0; c < 4; c++) atomicAdd(&dst[4 * lane + c], a[c]);
        #pragma unroll
        for (int c = 0; c < 4; c++) atomicAdd(&dst[256 + 4 * lane + c], a[4 + c]);
        #pragma unroll
        for (int c = 0; c < 4; c++) atomicAdd(&dst[512 + 4 * lane + c], a[8 + c]);
        #pragma unroll
        for (int c = 0; c < 4; c++) atomicAdd(&dst[768 + 4 * lane + c], a[12 + c]);
    }
}

// ---------------- sp[bin][c] = silu(pooled) : 4-way k-split ----------------
__global__ __launch_bounds__(1024) void k_sp(
    const float* __restrict__ s128, const float* __restrict__ s1024,
    const int* __restrict__ offs, const int* __restrict__ seq_len,
    const float* __restrict__ W_dc, const float* __restrict__ b_dc,
    const float* __restrict__ W_down, const float* __restrict__ b_down,
    float* __restrict__ sp) {
    __shared__ float red[4][DWN];
    int bin = blockIdx.x;
    int b = bin >> 5, t = bin & 31;
    int c = threadIdx.x & 255, ks = threadIdx.x >> 8;
    int C = offs[b + 1] - offs[b];
    int sl = seq_len[b];
    int L = C + sl;
    int start = (t * L) / TP;
    int end = ((t + 1) * L + TP - 1) / TP;
    int cnt = end - start;
    int ce = min(end, C);
    int n_ctx = max(ce - start, 0);
    int n_hs = max(end - C, 0) - max(start - C, 0);
    float p = 0.f;
    int k0 = ks * 288, k1 = k0 + 288;
    for (int k = k0; k < k1; k++) {
        if (k < F) p += s128[(size_t)bin * F + k] * W_dc[k * DWN + c];
        else {
            int kk = k - F;
            p += s1024[(size_t)bin * HID + kk] * W_down[kk * DWN + c];
        }
    }
    red[ks][c] = p;
    __syncthreads();
    if (ks == 0) {
        p = (red[0][c] + red[1][c]) + (red[2][c] + red[3][c])
            + (float)n_ctx * b_dc[c] + (float)n_hs * b_down[c];
        p /= (float)cnt;
        sp[(size_t)bin * DWN + c] = p / (1.f + __expf(-p));
    }
}

// ---------------- out[bin][o] = sp[bin] . W_up[:,o] + b_up ----------------
__global__ __launch_bounds__(256) void k_up(
    const float* __restrict__ sp, const float* __restrict__ W_up,
    const float* __restrict__ b_up, float* __restrict__ out) {
    __shared__ float s[DWN];
    int bin = blockIdx.x >> 2, q = blockIdx.x & 3;
    int tid = threadIdx.x;
    s[tid] = sp[(size_t)bin * DWN + tid];
    __syncthreads();
    int o = q * 256 + tid;
    float a0 = 0.f, a1 = 0.f, a2 = 0.f, a3 = 0.f;
    #pragma unroll 4
    for (int k = 0; k < DWN; k += 4) {
        a0 += s[k + 0] * W_up[(size_t)(k + 0) * HID + o];
        a1 += s[k + 1] * W_up[(size_t)(k + 1) * HID + o];
        a2 += s[k + 2] * W_up[(size_t)(k + 2) * HID + o];
        a3 += s[k + 3] * W_up[(size_t)(k + 3) * HID + o];
    }
    out[(size_t)bin * HID + o] = (a0 + a1) + (a2 + a3) + b_up[o];
}

extern "C" void kernel_launch(void* const* d_in, const int* in_sizes, int n_in,
                              void* d_out, int out_size, void* d_ws, size_t ws_size,
                              hipStream_t stream) {
    const int*   graph_x   = (const int*)d_in[0];
    const int*   edge_idx  = (const int*)d_in[1];
    const int*   batch_ids = (const int*)d_in[2];
    const float* hidden    = (const float*)d_in[3];
    const int*   seq_len   = (const int*)d_in[4];
    const float* emb       = (const float*)d_in[5];
    const float* gat_W     = (const float*)d_in[6];
    const float* gat_as    = (const float*)d_in[7];
    const float* gat_ad    = (const float*)d_in[8];
    const float* gat_b     = (const float*)d_in[9];
    const float* W_down    = (const float*)d_in[10];
    const float* b_down    = (const float*)d_in[11];
    const float* W_dc      = (const float*)d_in[12];
    const float* b_dc      = (const float*)d_in[13];
    const float* W_up      = (const float*)d_in[14];
    const float* b_up      = (const float*)d_in[15];
    float* out = (float*)d_out;

    char* ws = (char*)d_ws;
    ushort* bufA   = (ushort*)(ws);                   // x bf16, 25,600,000 B
    ushort* Wt     = (ushort*)(ws + 26000000);        // 98,304 B
    ushort* hb     = (ushort*)(ws + 51200000);        // h bf16, 25,600,000 B
    float*  s128   = (float*) (ws + 80000000);        // 131,072 B
    float*  s1024  = (float*) (ws + 80131072);        // 1,048,576 B
    float*  sp     = (float*) (ws + 81179648);        // 262,144 B
    uint*   stage  = (uint*)  (ws + 82000000);        // 196*5120*4 = 4,014,080 B
    float*  hs_src = (float*) (ws + 102400000);
    float*  hs_dst = (float*) (ws + 102800000);
    int*    bcur   = (int*)   (ws + 103200000);       // 784 B
    int*    cbase  = (int*)   (ws + 103310000);       // 788 B
    int*    indptr = (int*)   (ws + 103600000);       // 400,004 B
    int*    srcs   = (int*)   (ws + 104400128);       // 3,600,000 B
    int*    offs   = (int*)   (ws + 108002128);       // 36 B

    hipMemsetAsync(bcur, 0, NCB * sizeof(int), stream);
    k_offsets<<<(NN + 255) / 256, 256, 0, stream>>>(batch_ids, offs);
    k_embed<<<NN * 16 / 256, 256, 0, stream>>>(graph_x, emb, bufA);
    k_wconv<<<384, 128, 0, stream>>>(gat_W, Wt);
    k_part<<<(E2 + EPB - 1) / EPB, 256, 0, stream>>>(edge_idx, bcur, stage);
    k_cboff<<<1, 64, 0, stream>>>(bcur, cbase, indptr);
    k_sort2<<<NCB, 256, 0, stream>>>(stage, bcur, cbase, indptr, srcs);

    for (int l = 0; l < 3; l++) {
        k_gemm<<<(NN + 127) / 128, 256, 0, stream>>>(bufA, Wt + l * F * F, gat_as + l * F,
                                                     gat_ad + l * F, hb, hs_src, hs_dst);
        k_agg<<<(NN + 3) / 4, 256, 0, stream>>>(hb, srcs, indptr, hs_src, hs_dst,
                                                gat_b + l * F, bufA, (l < 2) ? 1 : 0);
    }

    hipMemsetAsync((void*)s128, 0, 131072 + 1048576, stream);
    k_binsum_ctx<<<391, 256, 0, stream>>>(bufA, batch_ids, offs, seq_len, s128);
    k_binsum_hid<<<256, 256, 0, stream>>>(hidden, offs, seq_len, s1024);
    k_sp<<<NB * TP, 1024, 0, stream>>>(s128, s1024, offs, seq_len,
                                       W_dc, b_dc, W_down, b_down, sp);
    k_up<<<NB * TP * 4, 256, 0, stream>>>(sp, W_up, b_up, out);
}

// Round 11
// 355.774 us; speedup vs baseline: 1.1229x; 1.1229x over previous
//
#include <hip/hip_runtime.h>
#include <hip/hip_bf16.h>

#define NN 100000   // nodes
#define NE 800000   // edges (without self loops)
#define E2 900000   // edges + self loops
#define F  128      // KGE
#define NB 8        // batch
#define SEQ 1024
#define HID 1024
#define DWN 256
#define TP 32
#define NCB 196     // coarse dst-buckets of 512 nodes (196*512 = 100352 >= NN)
#define CCAP 5120   // slab cap per bucket (expected 4592, sigma 68 -> 7.8 sigma slack)
#define EPB 4096    // edges per k_part block

typedef __attribute__((ext_vector_type(4))) float f32x4;
typedef __attribute__((ext_vector_type(8))) short s16x8;

__device__ __forceinline__ float BL(uint u) { return __uint_as_float(u << 16); }
__device__ __forceinline__ float BH(uint u) { return __uint_as_float(u & 0xffff0000u); }
__device__ __forceinline__ uint PK(float lo, float hi) {
    __hip_bfloat16 a = __float2bfloat16(lo);
    __hip_bfloat16 b = __float2bfloat16(hi);
    return (uint)(*(ushort*)&a) | ((uint)(*(ushort*)&b) << 16);
}
__device__ __forceinline__ ushort B1(float v) {
    __hip_bfloat16 a = __float2bfloat16(v);
    return *(ushort*)&a;
}
// floor(a/L) via float reciprocal + fixup; exact for 0<=a<2^24, 0<L<2^24
__device__ __forceinline__ int fdivq(int a, int L, float rcL) {
    int t = __float2int_rz((float)a * rcL);
    if (t * L > a) t--;
    else if ((t + 1) * L <= a) t++;
    return t;
}

// ---------------- batch offsets from sorted batch_ids ----------------
__global__ void k_offsets(const int* __restrict__ bids, int* __restrict__ offs) {
    int n = blockIdx.x * 256 + threadIdx.x;
    if (n >= NN) return;
    int b = bids[n];
    if (n == 0) offs[0] = 0;
    else if (bids[n - 1] != b) offs[b] = n;
    if (n == NN - 1) offs[b + 1] = NN;
}

// ---------------- embedding gather: x[n] = bf16(emb[graph_x[n]]) ----------------
__global__ void k_embed(const int* __restrict__ gx, const float* __restrict__ emb,
                        ushort* __restrict__ x) {
    int i = blockIdx.x * 256 + threadIdx.x;   // over NN*16 chunks of 8 cols
    int n = i >> 4, c = i & 15;
    const float4* src = (const float4*)(emb + (size_t)gx[n] * F + c * 8);
    float4 a = src[0], b = src[1];
    uint4 o;
    o.x = PK(a.x, a.y); o.y = PK(a.z, a.w);
    o.z = PK(b.x, b.y); o.w = PK(b.z, b.w);
    *(uint4*)&x[(size_t)n * F + c * 8] = o;
}

// ---------------- W transpose+bf16: wt[l][col][k] = bf16(W[l][k][col]) ----------
__global__ void k_wconv(const float* __restrict__ W, ushort* __restrict__ wt) {
    int l = blockIdx.x >> 7, col = blockIdx.x & 127, k = threadIdx.x;
    wt[l * 16384 + col * 128 + k] = B1(W[l * 16384 + k * 128 + col]);
}

// ---------------- CSR pass 1: partition edges into coarse buckets ----------------
__global__ __launch_bounds__(256) void k_part(const int* __restrict__ ei,
                                              int* __restrict__ bcur,
                                              uint* __restrict__ stage) {
    __shared__ int lcnt[NCB], gbase[NCB], lpos[NCB];
    int t = threadIdx.x;
    int e0 = blockIdx.x * EPB;
    for (int i = t; i < NCB; i += 256) { lcnt[i] = 0; lpos[i] = 0; }
    __syncthreads();
    for (int i = t; i < EPB; i += 256) {
        int e = e0 + i; if (e >= E2) break;
        int dst = (e < NE) ? ei[NE + e] : (e - NE);
        atomicAdd(&lcnt[dst >> 9], 1);
    }
    __syncthreads();
    for (int i = t; i < NCB; i += 256)
        if (lcnt[i] > 0) gbase[i] = atomicAdd(&bcur[i], lcnt[i]);
    __syncthreads();
    for (int i = t; i < EPB; i += 256) {
        int e = e0 + i; if (e >= E2) break;
        int src, dst;
        if (e < NE) { src = ei[e]; dst = ei[NE + e]; }
        else        { src = dst = e - NE; }
        int b = dst >> 9;
        int r = atomicAdd(&lpos[b], 1);
        int pos = gbase[b] + r;
        if (pos < CCAP) stage[(size_t)b * CCAP + pos] = ((uint)src << 9) | (uint)(dst & 511);
    }
}

// ---------------- bucket base scan ----------------
__global__ void k_cboff(const int* __restrict__ bcur, int* __restrict__ cbase,
                        int* __restrict__ indptr) {
    if (threadIdx.x == 0) {
        int r = 0;
        for (int i = 0; i < NCB; i++) { cbase[i] = r; r += min(bcur[i], CCAP); }
        cbase[NCB] = r;
        indptr[NN] = r;
    }
}

// ---------------- CSR pass 2: per-bucket sort (LDS hist + scan + scatter) -------
// srcs stores WORD offsets (src*64) so k_agg's gather needs no 64-bit mul.
__global__ __launch_bounds__(256) void k_sort2(
    const uint* __restrict__ stage, const int* __restrict__ bcur,
    const int* __restrict__ cbase, int* __restrict__ indptr,
    int* __restrict__ srcs) {
    __shared__ int lcur[512], sa[256], sb[256];
    __shared__ uint sorted[CCAP];
    int g = blockIdx.x, t = threadIdx.x;
    int ecnt = min(bcur[g], CCAP);
    int base = cbase[g];
    const uint* slab = stage + (size_t)g * CCAP;
    lcur[t] = 0; lcur[t + 256] = 0;
    __syncthreads();
    for (int i = t; i < ecnt; i += 256)
        atomicAdd(&lcur[slab[i] & 511u], 1);
    __syncthreads();
    int c0 = lcur[2 * t], c1 = lcur[2 * t + 1];
    sa[t] = c0 + c1; __syncthreads();
    int *s = sa, *d = sb;
    for (int off = 1; off < 256; off <<= 1) {
        int v = s[t]; if (t >= off) v += s[t - off];
        d[t] = v; __syncthreads();
        int* tmp = s; s = d; d = tmp;
    }
    int excl = s[t] - (c0 + c1);
    int n0 = g * 512 + 2 * t;
    if (n0 < NN) indptr[n0] = base + excl;
    if (n0 + 1 < NN) indptr[n0 + 1] = base + excl + c0;
    __syncthreads();
    lcur[2 * t] = excl; lcur[2 * t + 1] = excl + c0;
    __syncthreads();
    for (int i = t; i < ecnt; i += 256) {
        uint p = slab[i];
        int pos = atomicAdd(&lcur[p & 511u], 1);
        sorted[pos] = p >> 9;
    }
    __syncthreads();
    for (int i = t; i < ecnt; i += 256)
        srcs[base + i] = (int)(sorted[i] << 6);
}

// ---------------- MFMA GEMM: h = x @ W (bf16), fused hs epilogue ----------------
__global__ __launch_bounds__(256) void k_gemm(
    const ushort* __restrict__ xb, const ushort* __restrict__ wt,
    const float* __restrict__ a_s, const float* __restrict__ a_d,
    ushort* __restrict__ hb, float* __restrict__ hs_src, float* __restrict__ hs_dst) {
    __shared__ uint4 As[128 * 16];
    __shared__ uint4 Bs[128 * 16];
    const int tid = threadIdx.x;
    const int wave = tid >> 6, lane = tid & 63;
    const int row0 = blockIdx.x * 128;
    const int lr = lane & 15, lg = lane >> 4;

    #pragma unroll
    for (int p = 0; p < 8; p++) {
        int id = p * 256 + tid;
        int row = id >> 4, c16 = id & 15;
        int rg = row0 + row; if (rg >= NN) rg = NN - 1;
        As[row * 16 + (c16 ^ (row & 7))] = *(const uint4*)&xb[(size_t)rg * F + c16 * 8];
        Bs[row * 16 + (c16 ^ (row & 7))] = *(const uint4*)&wt[row * F + c16 * 8];
    }
    __syncthreads();

    f32x4 acc[2][8];
    #pragma unroll
    for (int m = 0; m < 2; m++)
        #pragma unroll
        for (int n = 0; n < 8; n++) acc[m][n] = (f32x4){0.f, 0.f, 0.f, 0.f};

    #pragma unroll
    for (int kt = 0; kt < 4; kt++) {
        s16x8 a[2], b[8];
        #pragma unroll
        for (int m = 0; m < 2; m++) {
            int row = 32 * wave + 16 * m + lr;
            a[m] = *reinterpret_cast<const s16x8*>(&As[row * 16 + ((kt * 4 + lg) ^ (row & 7))]);
        }
        #pragma unroll
        for (int n = 0; n < 8; n++) {
            int col = 16 * n + lr;
            b[n] = *reinterpret_cast<const s16x8*>(&Bs[col * 16 + ((kt * 4 + lg) ^ (col & 7))]);
        }
        #pragma unroll
        for (int m = 0; m < 2; m++)
            #pragma unroll
            for (int n = 0; n < 8; n++)
                acc[m][n] = __builtin_amdgcn_mfma_f32_16x16x32_bf16(a[m], b[n], acc[m][n], 0, 0, 0);
    }

    float asv[8], adv[8];
    #pragma unroll
    for (int n = 0; n < 8; n++) { asv[n] = a_s[16 * n + lr]; adv[n] = a_d[16 * n + lr]; }

    #pragma unroll
    for (int m = 0; m < 2; m++) {
        #pragma unroll
        for (int r = 0; r < 4; r++) {
            int rg = row0 + 32 * wave + 16 * m + lg * 4 + r;
            bool ok = rg < NN;
            float ps = 0.f, pd = 0.f;
            #pragma unroll
            for (int n = 0; n < 8; n++) {
                float v = acc[m][n][r];
                if (ok) hb[(size_t)rg * F + 16 * n + lr] = B1(v);
                ps += v * asv[n]; pd += v * adv[n];
            }
            #pragma unroll
            for (int msk = 8; msk >= 1; msk >>= 1) {
                ps += __shfl_xor(ps, msk);
                pd += __shfl_xor(pd, msk);
            }
            if (ok && lr == 0) { hs_src[rg] = ps; hs_dst[rg] = pd; }
        }
    }
}

// ---------------- per-node GAT aggregation (softmax over in-edges) ----------------
// R9 structure (low VGPR, occupancy-friendly); srcs holds word offsets.
__global__ __launch_bounds__(256) void k_agg(
    const ushort* __restrict__ hb, const int* __restrict__ srcs,
    const int* __restrict__ indptr, const float* __restrict__ hs_src,
    const float* __restrict__ hs_dst, const float* __restrict__ bias,
    ushort* __restrict__ xout, int do_relu) {
    __shared__ uint2 se[4][64];
    int wave = threadIdx.x >> 6, lane = threadIdx.x & 63;
    int i = blockIdx.x * 4 + wave;
    if (i >= NN) return;
    int p0 = indptr[i], p1 = indptr[i + 1];
    int deg = p1 - p0;
    float hd = hs_dst[i];
    const uint* hbw = (const uint*)hb;
    float ax0 = 0.f, ay0 = 0.f, ax1 = 0.f, ay1 = 0.f;
    float ax2 = 0.f, ay2 = 0.f, ax3 = 0.f, ay3 = 0.f, dl = 0.f;

    if (deg <= 64) {
        uint off = 0; float e = -1e30f;
        if (lane < deg) {
            off = (uint)srcs[p0 + lane];
            float t0 = hs_src[off >> 6] + hd;
            e = t0 > 0.f ? t0 : 0.2f * t0;
        }
        float m = e;
        #pragma unroll
        for (int o = 32; o > 0; o >>= 1) m = fmaxf(m, __shfl_xor(m, o));
        float ex = (lane < deg) ? __expf(e - m) : 0.f;
        dl = ex;
        se[wave][lane] = make_uint2(off, __float_as_uint(ex));
        int j = 0;
        for (; j + 4 <= deg; j += 4) {
            uint2 q0 = se[wave][j + 0], q1 = se[wave][j + 1];
            uint2 q2 = se[wave][j + 2], q3 = se[wave][j + 3];
            uint h0 = hbw[q0.x + lane];
            uint h1 = hbw[q1.x + lane];
            uint h2 = hbw[q2.x + lane];
            uint h3 = hbw[q3.x + lane];
            float e0 = __uint_as_float(q0.y), e1 = __uint_as_float(q1.y);
            float e2 = __uint_as_float(q2.y), e3 = __uint_as_float(q3.y);
            ax0 += e0 * BL(h0); ay0 += e0 * BH(h0);
            ax1 += e1 * BL(h1); ay1 += e1 * BH(h1);
            ax2 += e2 * BL(h2); ay2 += e2 * BH(h2);
            ax3 += e3 * BL(h3); ay3 += e3 * BH(h3);
        }
        for (; j < deg; j++) {
            uint2 q = se[wave][j];
            uint h = hbw[q.x + lane];
            float e0 = __uint_as_float(q.y);
            ax0 += e0 * BL(h); ay0 += e0 * BH(h);
        }
    } else {
        float m = -1e30f;
        for (int p = p0 + lane; p < p1; p += 64) {
            uint off = (uint)srcs[p];
            float e = hs_src[off >> 6] + hd;
            e = e > 0.f ? e : 0.2f * e;
            m = fmaxf(m, e);
        }
        #pragma unroll
        for (int o = 32; o > 0; o >>= 1) m = fmaxf(m, __shfl_xor(m, o));
        for (int base = p0; base < p1; base += 64) {
            int cn = min(64, p1 - base);
            uint off = 0; float ex = 0.f;
            if (lane < cn) {
                off = (uint)srcs[base + lane];
                float e = hs_src[off >> 6] + hd;
                e = e > 0.f ? e : 0.2f * e;
                ex = __expf(e - m);
            }
            dl += ex;
            se[wave][lane] = make_uint2(off, __float_as_uint(ex));
            int j = 0;
            for (; j + 4 <= cn; j += 4) {
                uint2 q0 = se[wave][j + 0], q1 = se[wave][j + 1];
                uint2 q2 = se[wave][j + 2], q3 = se[wave][j + 3];
                uint h0 = hbw[q0.x + lane];
                uint h1 = hbw[q1.x + lane];
                uint h2 = hbw[q2.x + lane];
                uint h3 = hbw[q3.x + lane];
                float e0 = __uint_as_float(q0.y), e1 = __uint_as_float(q1.y);
                float e2 = __uint_as_float(q2.y), e3 = __uint_as_float(q3.y);
                ax0 += e0 * BL(h0); ay0 += e0 * BH(h0);
                ax1 += e1 * BL(h1); ay1 += e1 * BH(h1);
                ax2 += e2 * BL(h2); ay2 += e2 * BH(h2);
                ax3 += e3 * BL(h3); ay3 += e3 * BH(h3);
            }
            for (; j < cn; j++) {
                uint2 q = se[wave][j];
                uint h = hbw[q.x + lane];
                float e0 = __uint_as_float(q.y);
                ax0 += e0 * BL(h); ay0 += e0 * BH(h);
            }
        }
    }
    float accx = (ax0 + ax1) + (ax2 + ax3);
    float accy = (ay0 + ay1) + (ay2 + ay3);
    #pragma unroll
    for (int o = 32; o > 0; o >>= 1) dl += __shfl_xor(dl, o);
    float inv = 1.f / dl;
    float2 b2 = ((const float2*)bias)[lane];
    float ox = accx * inv + b2.x;
    float oy = accy * inv + b2.y;
    if (do_relu) { ox = fmaxf(ox, 0.f); oy = fmaxf(oy, 0.f); }
    ((uint*)xout)[(size_t)i * 64 + lane] = PK(ox, oy);
}

// ---------------- bin sums: ctx rows (x3 bf16, 128 cols) ----------------
__global__ __launch_bounds__(256) void k_binsum_ctx(
    const ushort* __restrict__ x3, const int* __restrict__ bids,
    const int* __restrict__ offs, const int* __restrict__ seq_len,
    float* __restrict__ s128) {
    int wid = blockIdx.x * 4 + (threadIdx.x >> 6);
    int lane = threadIdx.x & 63;
    int r0 = wid * 64;
    if (r0 >= NN) return;
    int r1 = min(r0 + 64, NN);
    float ax = 0.f, ay = 0.f;
    int cur = -1;
    int cb = -1, off = 0, C = 0, L = 1;
    float rcL = 1.f;
    for (int r = r0; r < r1; r++) {
        int b = bids[r];
        if (b != cb) {
            cb = b; off = offs[b]; C = offs[b + 1] - off; L = C + seq_len[b];
            rcL = 1.0f / (float)L;
        }
        int q = r - off;
        int tmin = fdivq(q * TP, L, rcL);
        int tmax = fdivq((q + 1) * TP - 1, L, rcL);
        uint v = ((const uint*)(x3 + (size_t)r * F))[lane];
        float vx = BL(v), vy = BH(v);
        int bin = b * TP + tmin;
        if (bin != cur) {
            if (cur >= 0) {
                atomicAdd(&s128[(size_t)cur * F + 2 * lane], ax);
                atomicAdd(&s128[(size_t)cur * F + 2 * lane + 1], ay);
            }
            cur = bin; ax = 0.f; ay = 0.f;
        }
        ax += vx; ay += vy;
        if (tmax != tmin) {
            atomicAdd(&s128[(size_t)(b * TP + tmax) * F + 2 * lane], vx);
            atomicAdd(&s128[(size_t)(b * TP + tmax) * F + 2 * lane + 1], vy);
        }
    }
    if (cur >= 0) {
        atomicAdd(&s128[(size_t)cur * F + 2 * lane], ax);
        atomicAdd(&s128[(size_t)cur * F + 2 * lane + 1], ay);
    }
}

// ---------------- bin sums: hidden rows (1024 cols), 8-row chunks ----------------
__global__ __launch_bounds__(256) void k_binsum_hid(
    const float* __restrict__ hidden, const int* __restrict__ offs,
    const int* __restrict__ seq_len, float* __restrict__ s1024) {
    int wid = blockIdx.x * 4 + (threadIdx.x >> 6);   // 0..1023
    int lane = threadIdx.x & 63;
    int b = wid >> 7;          // 128 chunks per batch
    int chunk = wid & 127;
    int sl = seq_len[b];
    int r0 = chunk * 8;
    if (r0 >= sl) return;
    int r1 = min(r0 + 8, sl);
    int C = offs[b + 1] - offs[b];
    int L = C + sl;
    float rcL = 1.0f / (float)L;
    float a[16];
    #pragma unroll
    for (int c = 0; c < 16; c++) a[c] = 0.f;
    int cur = -1;
    const float* hbase = hidden + (size_t)b * SEQ * HID;
    for (int r = r0; r < r1; r++) {
        int q = C + r;
        int tmin = fdivq(q * TP, L, rcL);
        int tmax = fdivq((q + 1) * TP - 1, L, rcL);
        const float4* row = (const float4*)(hbase + (size_t)r * HID);
        float4 v0 = row[lane], v1 = row[64 + lane], v2 = row[128 + lane], v3 = row[192 + lane];
        int bin = b * TP + tmin;
        if (bin != cur) {
            if (cur >= 0) {
                float* dst = s1024 + (size_t)cur * HID;
                #pragma unroll
                for (int c = 0; c < 4; c++) atomicAdd(&dst[4 * lane + c], a[c]);
                #pragma unroll
                for (int c = 0; c < 4; c++) atomicAdd(&dst[256 + 4 * lane + c], a[4 + c]);
                #pragma unroll
                for (int c = 0; c < 4; c++) atomicAdd(&dst[512 + 4 * lane + c], a[8 + c]);
                #pragma unroll
                for (int c = 0; c < 4; c++) atomicAdd(&dst[768 + 4 * lane + c], a[12 + c]);
            }
            cur = bin;
            #pragma unroll
            for (int c = 0; c < 16; c++) a[c] = 0.f;
        }
        a[0] += v0.x; a[1] += v0.y; a[2] += v0.z; a[3] += v0.w;
        a[4] += v1.x; a[5] += v1.y; a[6] += v1.z; a[7] += v1.w;
        a[8] += v2.x; a[9] += v2.y; a[10] += v2.z; a[11] += v2.w;
        a[12] += v3.x; a[13] += v3.y; a[14] += v3.z; a[15] += v3.w;
        if (tmax != tmin) {
            float* dst = s1024 + (size_t)(b * TP + tmax) * HID;
            atomicAdd(&dst[4 * lane + 0], v0.x); atomicAdd(&dst[4 * lane + 1], v0.y);
            atomicAdd(&dst[4 * lane + 2], v0.z); atomicAdd(&dst[4 * lane + 3], v0.w);
            atomicAdd(&dst[256 + 4 * lane + 0], v1.x); atomicAdd(&dst[256 + 4 * lane + 1], v1.y);
            atomicAdd(&dst[256 + 4 * lane + 2], v1.z); atomicAdd(&dst[256 + 4 * lane + 3], v1.w);
            atomicAdd(&dst[512 + 4 * lane + 0], v2.x); atomicAdd(&dst[512 + 4 * lane + 1], v2.y);
            atomicAdd(&dst[512 + 4 * lane + 2], v2.z); atomicAdd(&dst[512 + 4 * lane + 3], v2.w);
            atomicAdd(&dst[768 + 4 * lane + 0], v3.x); atomicAdd(&dst[768 + 4 * lane + 1], v3.y);
            atomicAdd(&dst[768 + 4 * lane + 2], v3.z); atomicAdd(&dst[768 + 4 * lane + 3], v3.w);
        }
    }
    if (cur >= 0) {
        float* dst = s1024 + (size_t)cur * HID;
        #pragma unroll
        for (int c = 0; c < 4; c++) atomicAdd(&dst[4 * lane + c], a[c]);
        #pragma unroll
        for (int c = 0; c < 4; c++) atomicAdd(&dst[256 + 4 * lane + c], a[4 + c]);
        #pragma unroll
        for (int c = 0; c < 4; c++) atomicAdd(&dst[512 + 4 * lane + c], a[8 + c]);
        #pragma unroll
        for (int c = 0; c < 4; c++) atomicAdd(&dst[768 + 4 * lane + c], a[12 + c]);
    }
}

// ---------------- sp[bin][c] = silu(pooled) : 4-way k-split ----------------
__global__ __launch_bounds__(1024) void k_sp(
    const float* __restrict__ s128, const float* __restrict__ s1024,
    const int* __restrict__ offs, const int* __restrict__ seq_len,
    const float* __restrict__ W_dc, const float* __restrict__ b_dc,
    const float* __restrict__ W_down, const float* __restrict__ b_down,
    float* __restrict__ sp) {
    __shared__ float red[4][DWN];
    int bin = blockIdx.x;
    int b = bin >> 5, t = bin & 31;
    int c = threadIdx.x & 255, ks = threadIdx.x >> 8;
    int C = offs[b + 1] - offs[b];
    int sl = seq_len[b];
    int L = C + sl;
    int start = (t * L) / TP;
    int end = ((t + 1) * L + TP - 1) / TP;
    int cnt = end - start;
    int ce = min(end, C);
    int n_ctx = max(ce - start, 0);
    int n_hs = max(end - C, 0) - max(start - C, 0);
    float p = 0.f;
    int k0 = ks * 288, k1 = k0 + 288;
    for (int k = k0; k < k1; k++) {
        if (k < F) p += s128[(size_t)bin * F + k] * W_dc[k * DWN + c];
        else {
            int kk = k - F;
            p += s1024[(size_t)bin * HID + kk] * W_down[kk * DWN + c];
        }
    }
    red[ks][c] = p;
    __syncthreads();
    if (ks == 0) {
        p = (red[0][c] + red[1][c]) + (red[2][c] + red[3][c])
            + (float)n_ctx * b_dc[c] + (float)n_hs * b_down[c];
        p /= (float)cnt;
        sp[(size_t)bin * DWN + c] = p / (1.f + __expf(-p));
    }
}

// ---------------- out[bin][o] = sp[bin] . W_up[:,o] + b_up ----------------
__global__ __launch_bounds__(256) void k_up(
    const float* __restrict__ sp, const float* __restrict__ W_up,
    const float* __restrict__ b_up, float* __restrict__ out) {
    __shared__ float s[DWN];
    int bin = blockIdx.x >> 2, q = blockIdx.x & 3;
    int tid = threadIdx.x;
    s[tid] = sp[(size_t)bin * DWN + tid];
    __syncthreads();
    int o = q * 256 + tid;
    float a0 = 0.f, a1 = 0.f, a2 = 0.f, a3 = 0.f;
    #pragma unroll 4
    for (int k = 0; k < DWN; k += 4) {
        a0 += s[k + 0] * W_up[(size_t)(k + 0) * HID + o];
        a1 += s[k + 1] * W_up[(size_t)(k + 1) * HID + o];
        a2 += s[k + 2] * W_up[(size_t)(k + 2) * HID + o];
        a3 += s[k + 3] * W_up[(size_t)(k + 3) * HID + o];
    }
    out[(size_t)bin * HID + o] = (a0 + a1) + (a2 + a3) + b_up[o];
}

extern "C" void kernel_launch(void* const* d_in, const int* in_sizes, int n_in,
                              void* d_out, int out_size, void* d_ws, size_t ws_size,
                              hipStream_t stream) {
    const int*   graph_x   = (const int*)d_in[0];
    const int*   edge_idx  = (const int*)d_in[1];
    const int*   batch_ids = (const int*)d_in[2];
    const float* hidden    = (const float*)d_in[3];
    const int*   seq_len   = (const int*)d_in[4];
    const float* emb       = (const float*)d_in[5];
    const float* gat_W     = (const float*)d_in[6];
    const float* gat_as    = (const float*)d_in[7];
    const float* gat_ad    = (const float*)d_in[8];
    const float* gat_b     = (const float*)d_in[9];
    const float* W_down    = (const float*)d_in[10];
    const float* b_down    = (const float*)d_in[11];
    const float* W_dc      = (const float*)d_in[12];
    const float* b_dc      = (const float*)d_in[13];
    const float* W_up      = (const float*)d_in[14];
    const float* b_up      = (const float*)d_in[15];
    float* out = (float*)d_out;

    char* ws = (char*)d_ws;
    ushort* bufA   = (ushort*)(ws);                   // x bf16, 25,600,000 B
    ushort* Wt     = (ushort*)(ws + 26000000);        // 98,304 B
    ushort* hb     = (ushort*)(ws + 51200000);        // h bf16, 25,600,000 B
    float*  s128   = (float*) (ws + 80000000);        // 131,072 B
    float*  s1024  = (float*) (ws + 80131072);        // 1,048,576 B
    float*  sp     = (float*) (ws + 81179648);        // 262,144 B
    uint*   stage  = (uint*)  (ws + 82000000);        // 196*5120*4 = 4,014,080 B
    float*  hs_src = (float*) (ws + 102400000);
    float*  hs_dst = (float*) (ws + 102800000);
    int*    bcur   = (int*)   (ws + 103200000);       // 784 B
    int*    cbase  = (int*)   (ws + 103310000);       // 788 B
    int*    indptr = (int*)   (ws + 103600000);       // 400,004 B
    int*    srcs   = (int*)   (ws + 104400128);       // 3,600,000 B
    int*    offs   = (int*)   (ws + 108002128);       // 36 B

    hipMemsetAsync(bcur, 0, NCB * sizeof(int), stream);
    k_offsets<<<(NN + 255) / 256, 256, 0, stream>>>(batch_ids, offs);
    k_embed<<<NN * 16 / 256, 256, 0, stream>>>(graph_x, emb, bufA);
    k_wconv<<<384, 128, 0, stream>>>(gat_W, Wt);
    k_part<<<(E2 + EPB - 1) / EPB, 256, 0, stream>>>(edge_idx, bcur, stage);
    k_cboff<<<1, 64, 0, stream>>>(bcur, cbase, indptr);
    k_sort2<<<NCB, 256, 0, stream>>>(stage, bcur, cbase, indptr, srcs);

    for (int l = 0; l < 3; l++) {
        k_gemm<<<(NN + 127) / 128, 256, 0, stream>>>(bufA, Wt + l * F * F, gat_as + l * F,
                                                     gat_ad + l * F, hb, hs_src, hs_dst);
        k_agg<<<(NN + 3) / 4, 256, 0, stream>>>(hb, srcs, indptr, hs_src, hs_dst,
                                                gat_b + l * F, bufA, (l < 2) ? 1 : 0);
    }

    hipMemsetAsync((void*)s128, 0, 131072 + 1048576, stream);
    k_binsum_ctx<<<391, 256, 0, stream>>>(bufA, batch_ids, offs, seq_len, s128);
    k_binsum_hid<<<256, 256, 0, stream>>>(hidden, offs, seq_len, s1024);
    k_sp<<<NB * TP, 1024, 0, stream>>>(s128, s1024, offs, seq_len,
                                       W_dc, b_dc, W_down, b_down, sp);
    k_up<<<NB * TP * 4, 256, 0, stream>>>(sp, W_up, b_up, out);
}